// Round 4
// baseline (596.863 us; speedup 1.0000x reference)
//
#include <hip/hip_runtime.h>
#include <math.h>

#define TPB 256
#define NXCD 8

// ===================== threefry2x32-20 (JAX-exact, PARTITIONABLE mode) + gumbel =====================
__device__ __forceinline__ float jax_gumbel(unsigned key, unsigned i) {
  unsigned x0 = 0u, x1 = i;
  unsigned ks0 = 0u, ks1 = key, ks2 = key ^ 0x1BD11BDAu;
  x0 += ks0; x1 += ks1;
#define TFR(r) { x0 += x1; x1 = (x1 << (r)) | (x1 >> (32 - (r))); x1 ^= x0; }
  TFR(13) TFR(15) TFR(26) TFR(6)
  x0 += ks1; x1 += ks2 + 1u;
  TFR(17) TFR(29) TFR(16) TFR(24)
  x0 += ks2; x1 += ks0 + 2u;
  TFR(13) TFR(15) TFR(26) TFR(6)
  x0 += ks0; x1 += ks1 + 3u;
  TFR(17) TFR(29) TFR(16) TFR(24)
  x0 += ks1; x1 += ks2 + 4u;
  TFR(13) TFR(15) TFR(26) TFR(6)
  x0 += ks2; x1 += ks0 + 5u;
#undef TFR
  unsigned bits = x0 ^ x1;
  float f = __uint_as_float((bits >> 9) | 0x3f800000u) - 1.0f;
  float u = (f == 0.0f) ? 1.17549435e-38f : f;
  return -logf(-logf(u));
}

// ===================== degree count + slot capture (XCD-privatized) =====================
// Each block atomics into count copy (blockIdx & 7). On MI300-series blocks round-robin
// across the 8 XCDs, so each copy's lines stay in one XCD's L2 (no cross-XCD ping-pong).
// Correctness does NOT depend on the mapping (device-scope atomics either way).
__global__ void count_slot_x_k(const int4* __restrict__ col4, int* __restrict__ cnt8,
                               int4* __restrict__ slot4, int ne4, int NPi) {
  int i = blockIdx.x * TPB + threadIdx.x;
  int* mycnt = cnt8 + (size_t)(blockIdx.x & (NXCD - 1)) * NPi;
  if (i < ne4) {
    int4 c = col4[i];
    int4 s;
    s.x = atomicAdd(&mycnt[c.x], 1);
    s.y = atomicAdd(&mycnt[c.y], 1);
    s.z = atomicAdd(&mycnt[c.z], 1);
    s.w = atomicAdd(&mycnt[c.w], 1);
    slot4[i] = s;
  }
}

__global__ void count_slot_x_sc_k(const int* __restrict__ col, int* __restrict__ cnt8,
                                  int* __restrict__ slot, int ne, int NPi) {
  int i = blockIdx.x * TPB + threadIdx.x;
  int* mycnt = cnt8 + (size_t)(blockIdx.x & (NXCD - 1)) * NPi;
  if (i < ne) slot[i] = atomicAdd(&mycnt[col[i]], 1);
}

// per-node: prefix the 8 copies -> per-copy base (in place), total -> cnt
__global__ void combine_k(int* __restrict__ cnt8, int* __restrict__ cnt, int n, int NPi) {
  int i = blockIdx.x * TPB + threadIdx.x;
  if (i >= n) return;
  int run = 0;
#pragma unroll
  for (int k = 0; k < NXCD; k++) {
    int v = cnt8[(size_t)k * NPi + i];
    cnt8[(size_t)k * NPi + i] = run;
    run += v;
  }
  cnt[i] = run;
}

// ===================== blocked exclusive scan (1024 elems/block) =====================
__global__ void scan1_k(const int* __restrict__ cnt, int* __restrict__ bsums, int n) {
  int t = threadIdx.x;
  int base = blockIdx.x * 1024 + t * 4;
  int s = 0;
#pragma unroll
  for (int k = 0; k < 4; k++) { int i = base + k; if (i < n) s += cnt[i]; }
  __shared__ int red[TPB];
  red[t] = s; __syncthreads();
  for (int st = 128; st > 0; st >>= 1) { if (t < st) red[t] += red[t + st]; __syncthreads(); }
  if (t == 0) bsums[blockIdx.x] = red[0];
}

__global__ void scan2_k(int* bsums, int nb) {
  if (threadIdx.x == 0 && blockIdx.x == 0) {
    int run = 0;
    for (int b = 0; b < nb; b++) { int v = bsums[b]; bsums[b] = run; run += v; }
    bsums[nb] = run;
  }
}

__global__ void scan3_k(const int* __restrict__ cnt, const int* __restrict__ bsums,
                        int* __restrict__ rowptr, int n, int nb) {
  int t = threadIdx.x;
  int base = blockIdx.x * 1024 + t * 4;
  int v[4]; int tsum = 0;
#pragma unroll
  for (int k = 0; k < 4; k++) { v[k] = (base + k < n) ? cnt[base + k] : 0; tsum += v[k]; }
  __shared__ int sc[TPB];
  sc[t] = tsum; __syncthreads();
  for (int off = 1; off < TPB; off <<= 1) {
    int add = (t >= off) ? sc[t - off] : 0;
    __syncthreads();
    sc[t] += add;
    __syncthreads();
  }
  int excl = sc[t] - tsum + bsums[blockIdx.x];
#pragma unroll
  for (int k = 0; k < 4; k++) { if (base + k < n) rowptr[base + k] = excl; excl += v[k]; }
  if (blockIdx.x == 0 && t == 0) rowptr[n] = bsums[nb];
}

// ===================== CSR scatter (no atomics: rowptr + per-copy base + slot) =====================
__global__ void scatter_k(const int4* __restrict__ row4, const int4* __restrict__ col4,
                          const int4* __restrict__ slot4, const int* __restrict__ rowptr,
                          const int* __restrict__ cnt8, int* __restrict__ srcout,
                          int ne4, int NPi) {
  int i = blockIdx.x * TPB + threadIdx.x;
  const int* base = cnt8 + (size_t)(blockIdx.x & (NXCD - 1)) * NPi;
  if (i < ne4) {
    int4 c = col4[i];
    int4 r = row4[i];
    int4 s = slot4[i];
    srcout[rowptr[c.x] + base[c.x] + s.x] = r.x;
    srcout[rowptr[c.y] + base[c.y] + s.y] = r.y;
    srcout[rowptr[c.z] + base[c.z] + s.z] = r.z;
    srcout[rowptr[c.w] + base[c.w] + s.w] = r.w;
  }
}

__global__ void scatter_sc_k(const int* __restrict__ row, const int* __restrict__ col,
                             const int* __restrict__ slot, const int* __restrict__ rowptr,
                             const int* __restrict__ cnt8, int* __restrict__ srcout,
                             int ne, int NPi) {
  int i = blockIdx.x * TPB + threadIdx.x;
  const int* base = cnt8 + (size_t)(blockIdx.x & (NXCD - 1)) * NPi;
  if (i < ne) {
    int c = col[i];
    srcout[rowptr[c] + base[c] + slot[i]] = row[i];
  }
}

__global__ void dinv_k(const int* __restrict__ cnt, float* __restrict__ dinv, int n) {
  int i = blockIdx.x * TPB + threadIdx.x;
  if (i < n) dinv[i] = 1.0f / sqrtf((float)(cnt[i] + 1));
}

// ===================== micro-GEMM: out[n,FOUT] = epilogue(h[n,FIN] @ W) =====================
template <int FIN, int FOUT, int FP, int MODE>
__global__ void gemm_k(const float* __restrict__ A, const float* __restrict__ A2, int nsplit,
                       const float* __restrict__ W, const float* __restrict__ bias,
                       const float* __restrict__ dinv, float* __restrict__ out, int n) {
  constexpr int NODES = TPB / FP;
  __shared__ float Ws[FIN * FOUT];
  __shared__ float Hs[NODES * (FIN + 1)];
  int t = threadIdx.x;
  int base = blockIdx.x * NODES;
  for (int i = t; i < FIN * FOUT; i += TPB) Ws[i] = W[i];
  for (int i = t; i < NODES * FIN; i += TPB) {
    int nl = i / FIN, k = i - nl * FIN;
    int g = base + nl;
    float v = 0.f;
    if (g < n) v = (g < nsplit) ? A[(size_t)g * FIN + k] : A2[(size_t)(g - nsplit) * FIN + k];
    Hs[nl * (FIN + 1) + k] = v;
  }
  __syncthreads();
  int nl = t / FP, j = t % FP;
  int g = base + nl;
  if (g < n && j < FOUT) {
    float acc = 0.f;
#pragma unroll
    for (int k = 0; k < FIN; k++) acc += Hs[nl * (FIN + 1) + k] * Ws[k * FOUT + j];
    if constexpr (MODE == 0) {
      out[(size_t)g * FOUT + j] = acc * dinv[g];
    } else {
      acc += bias[j];
      acc = fminf(fmaxf(acc, 0.f), 6.f);
      out[(size_t)g * FOUT + j] = acc;
    }
  }
}

// ===================== aggregation: one wave per dst node, float4 gathers =====================
template <int FOUT, int FP>
__global__ void agg4_k(const float4* __restrict__ ts, const int* __restrict__ src,
                       const int* __restrict__ rowptr, const float* __restrict__ dinv,
                       const float4* __restrict__ bias4, float4* __restrict__ out, int n) {
  constexpr int V = FOUT / 4;
  constexpr int EPW = 64 / FP;
  int wave = blockIdx.x * (TPB / 64) + (threadIdx.x >> 6);
  int lane = threadIdx.x & 63;
  int c = wave;
  if (c >= n) return;
  int gph = lane / FP;
  int j = lane % FP;
  int s = rowptr[c], e = rowptr[c + 1];
  float4 acc = make_float4(0.f, 0.f, 0.f, 0.f);
  if (j < V) {
    for (int p = s + gph; p < e; p += EPW) {
      int r = src[p];
      float4 v = ts[(size_t)r * V + j];
      acc.x += v.x; acc.y += v.y; acc.z += v.z; acc.w += v.w;
    }
  }
#pragma unroll
  for (int off = FP; off < 64; off <<= 1) {
    acc.x += __shfl_xor(acc.x, off, 64);
    acc.y += __shfl_xor(acc.y, off, 64);
    acc.z += __shfl_xor(acc.z, off, 64);
    acc.w += __shfl_xor(acc.w, off, 64);
  }
  if (gph == 0 && j < V) {
    float4 self = ts[(size_t)c * V + j];
    float4 b = bias4[j];
    float d = dinv[c];
    float4 o;
    o.x = d * (acc.x + self.x) + b.x;
    o.y = d * (acc.y + self.y) + b.y;
    o.z = d * (acc.z + self.z) + b.z;
    o.w = d * (acc.w + self.w) + b.w;
    out[(size_t)c * V + j] = o;
  }
}

// ===================== edge copy (int -> float, [2,ne] -> [2,ne+1]) =====================
__global__ void edgecopy4_k(const int4* __restrict__ ei4, float* __restrict__ outp, int ne) {
  int i = blockIdx.x * TPB + threadIdx.x;
  int ne4 = ne / 4;
  if (i < ne4) {
    int4 r = ei4[i];
    float4 f = make_float4((float)r.x, (float)r.y, (float)r.z, (float)r.w);
    ((float4*)outp)[i] = f;
    int4 c = ei4[ne4 + i];
    float* o1 = outp + (size_t)(ne + 1) + i * 4;
    o1[0] = (float)c.x; o1[1] = (float)c.y; o1[2] = (float)c.z; o1[3] = (float)c.w;
  }
}

__global__ void edgecopy_sc_k(const int* __restrict__ ei, float* __restrict__ outp, int ne) {
  int i = blockIdx.x * TPB + threadIdx.x;
  if (i < 2 * ne) {
    int r = (i >= ne);
    int e = i - r * ne;
    outp[(size_t)r * (ne + 1) + e] = (float)ei[i];
  }
}

// ===================== head second matvecs: slog/elog =====================
__global__ void head2_k(const float* __restrict__ hs, const float* __restrict__ he,
                        const float* __restrict__ ws2, const float* __restrict__ bs2,
                        const float* __restrict__ we2, const float* __restrict__ be2,
                        float* __restrict__ slog, float* __restrict__ elog, int n) {
  int i = blockIdx.x * TPB + threadIdx.x;
  if (i >= n) return;
  float s = bs2[0];
#pragma unroll
  for (int k = 0; k < 16; k++) s += hs[(size_t)i * 16 + k] * ws2[k];
  float ee = be2[0];
#pragma unroll
  for (int k = 0; k < 24; k++) ee += he[(size_t)i * 24 + k] * we2[k];
  slog[i] = s;
  elog[i] = ee;
}

// ===================== softmax reductions =====================
__global__ void rmax_k(const float* __restrict__ a, const float* __restrict__ b,
                       float* pa, float* pb, int n) {
  int t = threadIdx.x;
  float m1 = -3.402823466e+38f, m2 = -3.402823466e+38f;
  for (int i = blockIdx.x * TPB + t; i < n; i += gridDim.x * TPB) {
    m1 = fmaxf(m1, a[i]); m2 = fmaxf(m2, b[i]);
  }
  __shared__ float s1[TPB], s2[TPB];
  s1[t] = m1; s2[t] = m2; __syncthreads();
  for (int st = 128; st > 0; st >>= 1) {
    if (t < st) { s1[t] = fmaxf(s1[t], s1[t + st]); s2[t] = fmaxf(s2[t], s2[t + st]); }
    __syncthreads();
  }
  if (t == 0) { pa[blockIdx.x] = s1[0]; pb[blockIdx.x] = s2[0]; }
}

__global__ void rmax_fin_k(const float* pa, const float* pb, float* fsc, int nb) {
  int t = threadIdx.x;
  float m1 = (t < nb) ? pa[t] : -3.402823466e+38f;
  float m2 = (t < nb) ? pb[t] : -3.402823466e+38f;
  __shared__ float s1[TPB], s2[TPB];
  s1[t] = m1; s2[t] = m2; __syncthreads();
  for (int st = 128; st > 0; st >>= 1) {
    if (t < st) { s1[t] = fmaxf(s1[t], s1[t + st]); s2[t] = fmaxf(s2[t], s2[t + st]); }
    __syncthreads();
  }
  if (t == 0) { fsc[0] = s1[0]; fsc[1] = s2[0]; }
}

__global__ void rsum_k(const float* __restrict__ a, const float* __restrict__ b,
                       const float* __restrict__ fsc, float* pa, float* pb, int n) {
  int t = threadIdx.x;
  float smax = fsc[0], emax = fsc[1];
  float v1 = 0.f, v2 = 0.f;
  for (int i = blockIdx.x * TPB + t; i < n; i += gridDim.x * TPB) {
    v1 += expf(a[i] - smax); v2 += expf(b[i] - emax);
  }
  __shared__ float s1[TPB], s2[TPB];
  s1[t] = v1; s2[t] = v2; __syncthreads();
  for (int st = 128; st > 0; st >>= 1) {
    if (t < st) { s1[t] += s1[t + st]; s2[t] += s2[t + st]; }
    __syncthreads();
  }
  if (t == 0) { pa[blockIdx.x] = s1[0]; pb[blockIdx.x] = s2[0]; }
}

__global__ void rsum_fin_k(const float* pa, const float* pb, float* fsc, int nb) {
  int t = threadIdx.x;
  float v1 = (t < nb) ? pa[t] : 0.f;
  float v2 = (t < nb) ? pb[t] : 0.f;
  __shared__ float s1[TPB], s2[TPB];
  s1[t] = v1; s2[t] = v2; __syncthreads();
  for (int st = 128; st > 0; st >>= 1) {
    if (t < st) { s1[t] += s1[t + st]; s2[t] += s2[t + st]; }
    __syncthreads();
  }
  if (t == 0) { fsc[2] = s1[0]; fsc[3] = s2[0]; }
}

// ===================== prob writes (exact reference semantics) =====================
__global__ void probs_start_k(const float* __restrict__ slog, const float* __restrict__ fsc,
                              float* __restrict__ outp, int n, int ngraph) {
  int i = blockIdx.x * TPB + threadIdx.x;
  if (i >= n) return;
  float p = expf(slog[i] - fsc[0]) / fsc[2];
  if (i >= ngraph) p = 0.f;
  if (p == 0.f) p = 1e-10f;
  outp[i] = p;
}

__global__ void probs_end_k(const float* __restrict__ elog, const float* __restrict__ fsc,
                            const int* __restrict__ isc, float* __restrict__ outp, int n) {
  int i = blockIdx.x * TPB + threadIdx.x;
  if (i >= n) return;
  float p = expf(elog[i] - fsc[1]) / fsc[3];
  if (i == isc[0]) p = 0.f;
  if (p == 0.f) p = 1e-10f;
  outp[i] = p;
}

// ===================== gumbel argmax (categorical) =====================
__global__ void argmax_k(const float* __restrict__ probs, unsigned key, int n,
                         float* pval, int* pidx) {
  int t = threadIdx.x;
  float bv = -3.402823466e+38f;
  int bi = 0x7fffffff;
  for (int i = blockIdx.x * TPB + t; i < n; i += gridDim.x * TPB) {
    float v = logf(probs[i]) + jax_gumbel(key, (unsigned)i);
    if (v > bv) { bv = v; bi = i; }
  }
  __shared__ float sv[TPB]; __shared__ int si[TPB];
  sv[t] = bv; si[t] = bi; __syncthreads();
  for (int st = 128; st > 0; st >>= 1) {
    if (t < st) {
      float v2 = sv[t + st]; int i2 = si[t + st];
      if (v2 > sv[t] || (v2 == sv[t] && i2 < si[t])) { sv[t] = v2; si[t] = i2; }
    }
    __syncthreads();
  }
  if (t == 0) { pval[blockIdx.x] = sv[0]; pidx[blockIdx.x] = si[0]; }
}

__global__ void argmax_fin_k(const float* pval, const int* pidx, int nb,
                             int* isc, float* dnode) {
  int t = threadIdx.x;
  float bv = (t < nb) ? pval[t] : -3.402823466e+38f;
  int bi = (t < nb) ? pidx[t] : 0x7fffffff;
  __shared__ float sv[TPB]; __shared__ int si[TPB];
  sv[t] = bv; si[t] = bi; __syncthreads();
  for (int st = 128; st > 0; st >>= 1) {
    if (t < st) {
      float v2 = sv[t + st]; int i2 = si[t + st];
      if (v2 > sv[t] || (v2 == sv[t] && i2 < si[t])) { sv[t] = v2; si[t] = i2; }
    }
    __syncthreads();
  }
  if (t == 0) { isc[0] = si[0]; dnode[0] = (float)si[0]; }
}

__global__ void argmax_fin_end_k(const float* pval, const int* pidx, int nb,
                                 const int* isc, float* p_end, float* p_e0, float* p_e1) {
  int t = threadIdx.x;
  float bv = (t < nb) ? pval[t] : -3.402823466e+38f;
  int bi = (t < nb) ? pidx[t] : 0x7fffffff;
  __shared__ float sv[TPB]; __shared__ int si[TPB];
  sv[t] = bv; si[t] = bi; __syncthreads();
  for (int st = 128; st > 0; st >>= 1) {
    if (t < st) {
      float v2 = sv[t + st]; int i2 = si[t + st];
      if (v2 > sv[t] || (v2 == sv[t] && i2 < si[t])) { sv[t] = v2; si[t] = i2; }
    }
    __syncthreads();
  }
  if (t == 0) {
    int en = si[0];
    p_end[0] = (float)en;
    p_e0[0] = (float)isc[0];
    p_e1[0] = (float)en;
  }
}

// ===================== launch =====================
extern "C" void kernel_launch(void* const* d_in, const int* in_sizes, int n_in,
                              void* d_out, int out_size, void* d_ws, size_t ws_size,
                              hipStream_t stream) {
  const float* x    = (const float*)d_in[0];
  const float* cand = (const float*)d_in[1];
  const int*   ei   = (const int*)d_in[2];
  const float* W1 = (const float*)d_in[3];  const float* b1  = (const float*)d_in[4];
  const float* W2 = (const float*)d_in[5];  const float* b2  = (const float*)d_in[6];
  const float* W3 = (const float*)d_in[7];  const float* b3  = (const float*)d_in[8];
  const float* Ws1= (const float*)d_in[9];  const float* bs1 = (const float*)d_in[10];
  const float* Ws2= (const float*)d_in[11]; const float* bs2 = (const float*)d_in[12];
  const float* We1= (const float*)d_in[13]; const float* be1 = (const float*)d_in[14];
  const float* We2= (const float*)d_in[15]; const float* be2 = (const float*)d_in[16];

  const int nG = in_sizes[0] / 32, nC = in_sizes[1] / 32;
  const int n  = nG + nC;            // 101000
  const int ne = in_sizes[2] / 2;    // 3200000

  float* out = (float*)d_out;
  const size_t OFF1 = (size_t)n * 32;
  const size_t OFF2 = OFF1 + n;
  const size_t OFF3 = OFF2 + n;
  const size_t OFF4 = OFF3 + 1;
  const size_t OFF5 = OFF4 + 1;     // edge_index_new region: 2*(ne+1) floats

  // ---- workspace layout ----
  float* wf = (float*)d_ws;
  int*   wi = (int*)d_ws;
  size_t NP = (((size_t)n + 2) + 63) & ~(size_t)63;
  int NPi = (int)NP;
  size_t o = 0;
  int*   cnt   = wi + o; o += NP;
  int*   rp    = wi + o; o += NP;
  int*   bsums = wi + o; o += 256;
  float* dinv  = wf + o; o += NP;
  float* bufX  = wf + o; o += (size_t)n * 32 + 64;
  float* bufT  = wf + o; o += (size_t)n * 32 + 64;
  float* slogv = wf + o; o += NP;
  float* elogv = wf + o; o += NP;
  float* pmax  = wf + o; o += 512;
  float* psum  = wf + o; o += 512;
  float* aval  = wf + o; o += 512;
  int*   aidx  = wi + o; o += 512;
  float* fsc   = wf + o; o += 64;
  int*   isc   = wi + o; o += 64;

  // 8 XCD-private count copies alias bufX (8*NP ints = 3.2 MB << n*32 floats),
  // consumed (as per-copy bases) by scatter_k, then bufX is reused by agg layer 1.
  int* cnt8 = (int*)bufX;

  // slot + csr live in the edge_index_new output region (2*(ne+1) floats),
  // overwritten by edgecopy after the last aggregation.
  size_t pad = (4 - (OFF5 & 3)) & 3;
  bool vec_ok = (ne % 4 == 0) && (pad + 2 * (size_t)ne <= 2 * (size_t)(ne + 1));
  int* slot;
  int* csr;
  if (vec_ok) {
    slot = (int*)(out + OFF5 + pad);
    csr  = slot + ne;
  } else {
    slot = (int*)(out + OFF5);
    csr  = slot + ne;
  }

  const int* row = ei;
  const int* col = ei + ne;

  hipMemsetAsync(cnt8, 0, (size_t)NXCD * NP * sizeof(int), stream);

  int gN = (n + TPB - 1) / TPB;
  int nb = (n + 1023) / 1024;
  int ne4 = ne / 4;
  int gE4 = (ne4 + TPB - 1) / TPB;
  int gE  = (ne + TPB - 1) / TPB;

  if (vec_ok) {
    count_slot_x_k<<<gE4, TPB, 0, stream>>>((const int4*)col, cnt8, (int4*)slot, ne4, NPi);
  } else {
    count_slot_x_sc_k<<<gE, TPB, 0, stream>>>(col, cnt8, slot, ne, NPi);
  }
  combine_k<<<gN, TPB, 0, stream>>>(cnt8, cnt, n, NPi);
  scan1_k<<<nb, TPB, 0, stream>>>(cnt, bsums, n);
  scan2_k<<<1, 64, 0, stream>>>(bsums, nb);
  scan3_k<<<nb, TPB, 0, stream>>>(cnt, bsums, rp, n, nb);
  if (vec_ok) {
    scatter_k<<<gE4, TPB, 0, stream>>>((const int4*)row, (const int4*)col, (const int4*)slot,
                                       rp, cnt8, csr, ne4, NPi);
  } else {
    scatter_sc_k<<<gE, TPB, 0, stream>>>(row, col, slot, rp, cnt8, csr, ne, NPi);
  }
  dinv_k<<<gN, TPB, 0, stream>>>(cnt, dinv, n);

  // GCN layer 1: 32 -> 16
  gemm_k<32, 16, 16, 0><<<(n + 15) / 16, TPB, 0, stream>>>(x, cand, nG, W1, nullptr, dinv, bufT, n);
  agg4_k<16, 4><<<(n + 3) / 4, TPB, 0, stream>>>((const float4*)bufT, csr, rp, dinv,
                                                 (const float4*)b1, (float4*)bufX, n);
  // GCN layer 2: 16 -> 24
  gemm_k<16, 24, 32, 0><<<(n + 7) / 8, TPB, 0, stream>>>(bufX, bufX, n, W2, nullptr, dinv, bufT, n);
  agg4_k<24, 8><<<(n + 3) / 4, TPB, 0, stream>>>((const float4*)bufT, csr, rp, dinv,
                                                 (const float4*)b2, (float4*)bufX, n);
  // GCN layer 3: 24 -> 32 (h3 straight into d_out)
  gemm_k<24, 32, 32, 0><<<(n + 7) / 8, TPB, 0, stream>>>(bufX, bufX, n, W3, nullptr, dinv, bufT, n);
  agg4_k<32, 8><<<(n + 3) / 4, TPB, 0, stream>>>((const float4*)bufT, csr, rp, dinv,
                                                 (const float4*)b3, (float4*)out, n);

  // edge copy (overwrites slot + csr scratch)
  if (ne % 4 == 0) {
    edgecopy4_k<<<(ne4 + TPB - 1) / TPB, TPB, 0, stream>>>((const int4*)ei, out + OFF5, ne);
  } else {
    edgecopy_sc_k<<<(2 * ne + TPB - 1) / TPB, TPB, 0, stream>>>(ei, out + OFF5, ne);
  }

  // heads
  gemm_k<32, 16, 16, 1><<<(n + 15) / 16, TPB, 0, stream>>>(out, out, n, Ws1, bs1, dinv, bufX, n);
  gemm_k<32, 24, 32, 1><<<(n + 7) / 8, TPB, 0, stream>>>(out, out, n, We1, be1, dinv, bufT, n);
  head2_k<<<gN, TPB, 0, stream>>>(bufX, bufT, Ws2, bs2, We2, be2, slogv, elogv, n);

  // softmax reductions (both heads together)
  rmax_k<<<256, TPB, 0, stream>>>(slogv, elogv, pmax, pmax + 256, n);
  rmax_fin_k<<<1, TPB, 0, stream>>>(pmax, pmax + 256, fsc, 256);
  rsum_k<<<256, TPB, 0, stream>>>(slogv, elogv, fsc, psum, psum + 256, n);
  rsum_fin_k<<<1, TPB, 0, stream>>>(psum, psum + 256, fsc, 256);

  // start head: probs -> categorical(key 42)
  probs_start_k<<<gN, TPB, 0, stream>>>(slogv, fsc, out + OFF1, n, nG);
  argmax_k<<<256, TPB, 0, stream>>>(out + OFF1, 42u, n, aval, aidx);
  argmax_fin_k<<<1, TPB, 0, stream>>>(aval, aidx, 256, isc, out + OFF3);

  // end head: probs (zero at start_node) -> categorical(key 43)
  probs_end_k<<<gN, TPB, 0, stream>>>(elogv, fsc, isc, out + OFF2, n);
  argmax_k<<<256, TPB, 0, stream>>>(out + OFF2, 43u, n, aval + 256, aidx + 256);
  argmax_fin_end_k<<<1, TPB, 0, stream>>>(aval + 256, aidx + 256, 256, isc,
                                          out + OFF4, out + OFF5 + ne, out + OFF5 + 2 * (size_t)ne + 1);
}

// Round 5
// 485.270 us; speedup vs baseline: 1.2300x; 1.2300x over previous
//
#include <hip/hip_runtime.h>
#include <math.h>

#define TPB 256
#define BNODES 256     // nodes per bucket (col>>8)
#define EPB 4096       // edges per block in hist/bscatter

// ===================== threefry2x32-20 (JAX-exact, PARTITIONABLE mode) + gumbel =====================
__device__ __forceinline__ float jax_gumbel(unsigned key, unsigned i) {
  unsigned x0 = 0u, x1 = i;
  unsigned ks0 = 0u, ks1 = key, ks2 = key ^ 0x1BD11BDAu;
  x0 += ks0; x1 += ks1;
#define TFR(r) { x0 += x1; x1 = (x1 << (r)) | (x1 >> (32 - (r))); x1 ^= x0; }
  TFR(13) TFR(15) TFR(26) TFR(6)
  x0 += ks1; x1 += ks2 + 1u;
  TFR(17) TFR(29) TFR(16) TFR(24)
  x0 += ks2; x1 += ks0 + 2u;
  TFR(13) TFR(15) TFR(26) TFR(6)
  x0 += ks0; x1 += ks1 + 3u;
  TFR(17) TFR(29) TFR(16) TFR(24)
  x0 += ks1; x1 += ks2 + 4u;
  TFR(13) TFR(15) TFR(26) TFR(6)
  x0 += ks2; x1 += ks0 + 5u;
#undef TFR
  unsigned bits = x0 ^ x1;
  float f = __uint_as_float((bits >> 9) | 0x3f800000u) - 1.0f;
  float u = (f == 0.0f) ? 1.17549435e-38f : f;
  return -logf(-logf(u));
}

// ===================== pass 1a: coarse bucket histogram (LDS atomics only) =====================
__global__ void hist_k(const int* __restrict__ col, int* __restrict__ hist,
                       int ne, int nbkt, int nblk) {
  __shared__ int h[1024];
  int t = threadIdx.x;
  for (int i = t; i < nbkt; i += TPB) h[i] = 0;
  __syncthreads();
  int base = blockIdx.x * EPB;
#pragma unroll
  for (int k = 0; k < EPB / TPB; k++) {
    int idx = base + k * TPB + t;
    if (idx < ne) atomicAdd(&h[col[idx] >> 8], 1);
  }
  __syncthreads();
  for (int i = t; i < nbkt; i += TPB) hist[(size_t)i * nblk + blockIdx.x] = h[i];
}

// ===================== scans (generic, reused for the hist array) =====================
__global__ void scan1_k(const int* __restrict__ a, int* __restrict__ bsums, int n) {
  int t = threadIdx.x;
  int base = blockIdx.x * 1024 + t * 4;
  int s = 0;
#pragma unroll
  for (int k = 0; k < 4; k++) { int i = base + k; if (i < n) s += a[i]; }
  __shared__ int red[TPB];
  red[t] = s; __syncthreads();
  for (int st = 128; st > 0; st >>= 1) { if (t < st) red[t] += red[t + st]; __syncthreads(); }
  if (t == 0) bsums[blockIdx.x] = red[0];
}

// single-block exclusive scan for m <= 1024, appends total at a[m]
__global__ void scan_single_k(int* a, int m) {
  __shared__ int sc[TPB];
  int t = threadIdx.x;
  int v[4]; int s = 0;
#pragma unroll
  for (int k = 0; k < 4; k++) { int i = t * 4 + k; v[k] = (i < m) ? a[i] : 0; s += v[k]; }
  sc[t] = s; __syncthreads();
  for (int off = 1; off < TPB; off <<= 1) {
    int add = (t >= off) ? sc[t - off] : 0;
    __syncthreads();
    sc[t] += add;
    __syncthreads();
  }
  int excl = sc[t] - s;
#pragma unroll
  for (int k = 0; k < 4; k++) { int i = t * 4 + k; if (i < m) a[i] = excl; excl += v[k]; }
  if (t == TPB - 1) a[m] = excl;
}

__global__ void scan3_k(const int* __restrict__ a, const int* __restrict__ bsums,
                        int* __restrict__ outp, int n, int nb) {
  int t = threadIdx.x;
  int base = blockIdx.x * 1024 + t * 4;
  int v[4]; int tsum = 0;
#pragma unroll
  for (int k = 0; k < 4; k++) { v[k] = (base + k < n) ? a[base + k] : 0; tsum += v[k]; }
  __shared__ int sc[TPB];
  sc[t] = tsum; __syncthreads();
  for (int off = 1; off < TPB; off <<= 1) {
    int add = (t >= off) ? sc[t - off] : 0;
    __syncthreads();
    sc[t] += add;
    __syncthreads();
  }
  int excl = sc[t] - tsum + bsums[blockIdx.x];
#pragma unroll
  for (int k = 0; k < 4; k++) { if (base + k < n) outp[base + k] = excl; excl += v[k]; }
  if (blockIdx.x == 0 && t == 0) outp[n] = bsums[nb];
}

// ===================== pass 1b: scatter edges into bucket-sorted pairs (LDS atomics only) ===========
__global__ void bscatter_k(const int* __restrict__ row, const int* __restrict__ col,
                           const int* __restrict__ hist, int2* __restrict__ pairs,
                           int ne, int nbkt, int nblk) {
  __shared__ int base[1024];
  int t = threadIdx.x;
  for (int i = t; i < nbkt; i += TPB) base[i] = hist[(size_t)i * nblk + blockIdx.x];
  __syncthreads();
  int b0 = blockIdx.x * EPB;
#pragma unroll
  for (int k = 0; k < EPB / TPB; k++) {
    int idx = b0 + k * TPB + t;
    if (idx < ne) {
      int c = col[idx];
      int r = row[idx];
      int p = atomicAdd(&base[c >> 8], 1);
      pairs[p] = make_int2(r, c);
    }
  }
}

// ===================== pass 2: per-bucket CSR build (rowptr, dinv, csr; LDS only) =====================
__global__ void bbuild_k(const int2* __restrict__ pairs, const int* __restrict__ hist,
                         int nblk, int* __restrict__ rp, float* __restrict__ dinv,
                         int* __restrict__ csr, int n, int ne) {
  int bkt = blockIdx.x;
  int lo = bkt << 8;
  int t = threadIdx.x;
  int bstart = hist[(size_t)bkt * nblk];
  int bend   = hist[(size_t)(bkt + 1) * nblk];
  __shared__ int cnt[BNODES], sc[BNODES], pos[BNODES];
  cnt[t] = 0; __syncthreads();
  for (int p = bstart + t; p < bend; p += TPB) {
    int2 e = pairs[p];
    atomicAdd(&cnt[e.y - lo], 1);
  }
  __syncthreads();
  int own = cnt[t];
  sc[t] = own; __syncthreads();
  for (int off = 1; off < BNODES; off <<= 1) {
    int add = (t >= off) ? sc[t - off] : 0;
    __syncthreads();
    sc[t] += add;
    __syncthreads();
  }
  int excl = sc[t] - own;
  if (lo + t < n) {
    rp[lo + t] = bstart + excl;
    dinv[lo + t] = 1.0f / sqrtf((float)(own + 1));
  }
  pos[t] = bstart + excl;
  __syncthreads();
  for (int p = bstart + t; p < bend; p += TPB) {
    int2 e = pairs[p];
    int q = atomicAdd(&pos[e.y - lo], 1);
    csr[q] = e.x;
  }
  if (bkt == 0 && t == 0) rp[n] = ne;
}

// ===================== micro-GEMM: out[n,FOUT] = epilogue(h[n,FIN] @ W) =====================
template <int FIN, int FOUT, int FP, int MODE>
__global__ void gemm_k(const float* __restrict__ A, const float* __restrict__ A2, int nsplit,
                       const float* __restrict__ W, const float* __restrict__ bias,
                       const float* __restrict__ dinv, float* __restrict__ out, int n) {
  constexpr int NODES = TPB / FP;
  __shared__ float Ws[FIN * FOUT];
  __shared__ float Hs[NODES * (FIN + 1)];
  int t = threadIdx.x;
  int base = blockIdx.x * NODES;
  for (int i = t; i < FIN * FOUT; i += TPB) Ws[i] = W[i];
  for (int i = t; i < NODES * FIN; i += TPB) {
    int nl = i / FIN, k = i - nl * FIN;
    int g = base + nl;
    float v = 0.f;
    if (g < n) v = (g < nsplit) ? A[(size_t)g * FIN + k] : A2[(size_t)(g - nsplit) * FIN + k];
    Hs[nl * (FIN + 1) + k] = v;
  }
  __syncthreads();
  int nl = t / FP, j = t % FP;
  int g = base + nl;
  if (g < n && j < FOUT) {
    float acc = 0.f;
#pragma unroll
    for (int k = 0; k < FIN; k++) acc += Hs[nl * (FIN + 1) + k] * Ws[k * FOUT + j];
    if constexpr (MODE == 0) {
      out[(size_t)g * FOUT + j] = acc * dinv[g];
    } else {
      acc += bias[j];
      acc = fminf(fmaxf(acc, 0.f), 6.f);
      out[(size_t)g * FOUT + j] = acc;
    }
  }
}

// ===================== aggregation: one wave per dst node, float4 gathers =====================
template <int FOUT, int FP>
__global__ void agg4_k(const float4* __restrict__ ts, const int* __restrict__ src,
                       const int* __restrict__ rowptr, const float* __restrict__ dinv,
                       const float4* __restrict__ bias4, float4* __restrict__ out, int n) {
  constexpr int V = FOUT / 4;
  constexpr int EPW = 64 / FP;
  int wave = blockIdx.x * (TPB / 64) + (threadIdx.x >> 6);
  int lane = threadIdx.x & 63;
  int c = wave;
  if (c >= n) return;
  int gph = lane / FP;
  int j = lane % FP;
  int s = rowptr[c], e = rowptr[c + 1];
  float4 acc = make_float4(0.f, 0.f, 0.f, 0.f);
  if (j < V) {
    for (int p = s + gph; p < e; p += EPW) {
      int r = src[p];
      float4 v = ts[(size_t)r * V + j];
      acc.x += v.x; acc.y += v.y; acc.z += v.z; acc.w += v.w;
    }
  }
#pragma unroll
  for (int off = FP; off < 64; off <<= 1) {
    acc.x += __shfl_xor(acc.x, off, 64);
    acc.y += __shfl_xor(acc.y, off, 64);
    acc.z += __shfl_xor(acc.z, off, 64);
    acc.w += __shfl_xor(acc.w, off, 64);
  }
  if (gph == 0 && j < V) {
    float4 self = ts[(size_t)c * V + j];
    float4 b = bias4[j];
    float d = dinv[c];
    float4 o;
    o.x = d * (acc.x + self.x) + b.x;
    o.y = d * (acc.y + self.y) + b.y;
    o.z = d * (acc.z + self.z) + b.z;
    o.w = d * (acc.w + self.w) + b.w;
    out[(size_t)c * V + j] = o;
  }
}

// ===================== edge copy (int -> float, [2,ne] -> [2,ne+1]) =====================
__global__ void edgecopy4_k(const int4* __restrict__ ei4, float* __restrict__ outp, int ne) {
  int i = blockIdx.x * TPB + threadIdx.x;
  int ne4 = ne / 4;
  if (i < ne4) {
    int4 r = ei4[i];
    float4 f = make_float4((float)r.x, (float)r.y, (float)r.z, (float)r.w);
    ((float4*)outp)[i] = f;
    int4 c = ei4[ne4 + i];
    float* o1 = outp + (size_t)(ne + 1) + i * 4;
    o1[0] = (float)c.x; o1[1] = (float)c.y; o1[2] = (float)c.z; o1[3] = (float)c.w;
  }
}

__global__ void edgecopy_sc_k(const int* __restrict__ ei, float* __restrict__ outp, int ne) {
  int i = blockIdx.x * TPB + threadIdx.x;
  if (i < 2 * ne) {
    int r = (i >= ne);
    int e = i - r * ne;
    outp[(size_t)r * (ne + 1) + e] = (float)ei[i];
  }
}

// ===================== head second matvecs: slog/elog =====================
__global__ void head2_k(const float* __restrict__ hs, const float* __restrict__ he,
                        const float* __restrict__ ws2, const float* __restrict__ bs2,
                        const float* __restrict__ we2, const float* __restrict__ be2,
                        float* __restrict__ slog, float* __restrict__ elog, int n) {
  int i = blockIdx.x * TPB + threadIdx.x;
  if (i >= n) return;
  float s = bs2[0];
#pragma unroll
  for (int k = 0; k < 16; k++) s += hs[(size_t)i * 16 + k] * ws2[k];
  float ee = be2[0];
#pragma unroll
  for (int k = 0; k < 24; k++) ee += he[(size_t)i * 24 + k] * we2[k];
  slog[i] = s;
  elog[i] = ee;
}

// ===================== softmax reductions =====================
__global__ void rmax_k(const float* __restrict__ a, const float* __restrict__ b,
                       float* pa, float* pb, int n) {
  int t = threadIdx.x;
  float m1 = -3.402823466e+38f, m2 = -3.402823466e+38f;
  for (int i = blockIdx.x * TPB + t; i < n; i += gridDim.x * TPB) {
    m1 = fmaxf(m1, a[i]); m2 = fmaxf(m2, b[i]);
  }
  __shared__ float s1[TPB], s2[TPB];
  s1[t] = m1; s2[t] = m2; __syncthreads();
  for (int st = 128; st > 0; st >>= 1) {
    if (t < st) { s1[t] = fmaxf(s1[t], s1[t + st]); s2[t] = fmaxf(s2[t], s2[t + st]); }
    __syncthreads();
  }
  if (t == 0) { pa[blockIdx.x] = s1[0]; pb[blockIdx.x] = s2[0]; }
}

__global__ void rmax_fin_k(const float* pa, const float* pb, float* fsc, int nb) {
  int t = threadIdx.x;
  float m1 = (t < nb) ? pa[t] : -3.402823466e+38f;
  float m2 = (t < nb) ? pb[t] : -3.402823466e+38f;
  __shared__ float s1[TPB], s2[TPB];
  s1[t] = m1; s2[t] = m2; __syncthreads();
  for (int st = 128; st > 0; st >>= 1) {
    if (t < st) { s1[t] = fmaxf(s1[t], s1[t + st]); s2[t] = fmaxf(s2[t], s2[t + st]); }
    __syncthreads();
  }
  if (t == 0) { fsc[0] = s1[0]; fsc[1] = s2[0]; }
}

__global__ void rsum_k(const float* __restrict__ a, const float* __restrict__ b,
                       const float* __restrict__ fsc, float* pa, float* pb, int n) {
  int t = threadIdx.x;
  float smax = fsc[0], emax = fsc[1];
  float v1 = 0.f, v2 = 0.f;
  for (int i = blockIdx.x * TPB + t; i < n; i += gridDim.x * TPB) {
    v1 += expf(a[i] - smax); v2 += expf(b[i] - emax);
  }
  __shared__ float s1[TPB], s2[TPB];
  s1[t] = v1; s2[t] = v2; __syncthreads();
  for (int st = 128; st > 0; st >>= 1) {
    if (t < st) { s1[t] += s1[t + st]; s2[t] += s2[t + st]; }
    __syncthreads();
  }
  if (t == 0) { pa[blockIdx.x] = s1[0]; pb[blockIdx.x] = s2[0]; }
}

__global__ void rsum_fin_k(const float* pa, const float* pb, float* fsc, int nb) {
  int t = threadIdx.x;
  float v1 = (t < nb) ? pa[t] : 0.f;
  float v2 = (t < nb) ? pb[t] : 0.f;
  __shared__ float s1[TPB], s2[TPB];
  s1[t] = v1; s2[t] = v2; __syncthreads();
  for (int st = 128; st > 0; st >>= 1) {
    if (t < st) { s1[t] += s1[t + st]; s2[t] += s2[t + st]; }
    __syncthreads();
  }
  if (t == 0) { fsc[2] = s1[0]; fsc[3] = s2[0]; }
}

// ===================== prob writes (exact reference semantics) =====================
__global__ void probs_start_k(const float* __restrict__ slog, const float* __restrict__ fsc,
                              float* __restrict__ outp, int n, int ngraph) {
  int i = blockIdx.x * TPB + threadIdx.x;
  if (i >= n) return;
  float p = expf(slog[i] - fsc[0]) / fsc[2];
  if (i >= ngraph) p = 0.f;
  if (p == 0.f) p = 1e-10f;
  outp[i] = p;
}

__global__ void probs_end_k(const float* __restrict__ elog, const float* __restrict__ fsc,
                            const int* __restrict__ isc, float* __restrict__ outp, int n) {
  int i = blockIdx.x * TPB + threadIdx.x;
  if (i >= n) return;
  float p = expf(elog[i] - fsc[1]) / fsc[3];
  if (i == isc[0]) p = 0.f;
  if (p == 0.f) p = 1e-10f;
  outp[i] = p;
}

// ===================== gumbel argmax (categorical) =====================
__global__ void argmax_k(const float* __restrict__ probs, unsigned key, int n,
                         float* pval, int* pidx) {
  int t = threadIdx.x;
  float bv = -3.402823466e+38f;
  int bi = 0x7fffffff;
  for (int i = blockIdx.x * TPB + t; i < n; i += gridDim.x * TPB) {
    float v = logf(probs[i]) + jax_gumbel(key, (unsigned)i);
    if (v > bv) { bv = v; bi = i; }
  }
  __shared__ float sv[TPB]; __shared__ int si[TPB];
  sv[t] = bv; si[t] = bi; __syncthreads();
  for (int st = 128; st > 0; st >>= 1) {
    if (t < st) {
      float v2 = sv[t + st]; int i2 = si[t + st];
      if (v2 > sv[t] || (v2 == sv[t] && i2 < si[t])) { sv[t] = v2; si[t] = i2; }
    }
    __syncthreads();
  }
  if (t == 0) { pval[blockIdx.x] = sv[0]; pidx[blockIdx.x] = si[0]; }
}

__global__ void argmax_fin_k(const float* pval, const int* pidx, int nb,
                             int* isc, float* dnode) {
  int t = threadIdx.x;
  float bv = (t < nb) ? pval[t] : -3.402823466e+38f;
  int bi = (t < nb) ? pidx[t] : 0x7fffffff;
  __shared__ float sv[TPB]; __shared__ int si[TPB];
  sv[t] = bv; si[t] = bi; __syncthreads();
  for (int st = 128; st > 0; st >>= 1) {
    if (t < st) {
      float v2 = sv[t + st]; int i2 = si[t + st];
      if (v2 > sv[t] || (v2 == sv[t] && i2 < si[t])) { sv[t] = v2; si[t] = i2; }
    }
    __syncthreads();
  }
  if (t == 0) { isc[0] = si[0]; dnode[0] = (float)si[0]; }
}

__global__ void argmax_fin_end_k(const float* pval, const int* pidx, int nb,
                                 const int* isc, float* p_end, float* p_e0, float* p_e1) {
  int t = threadIdx.x;
  float bv = (t < nb) ? pval[t] : -3.402823466e+38f;
  int bi = (t < nb) ? pidx[t] : 0x7fffffff;
  __shared__ float sv[TPB]; __shared__ int si[TPB];
  sv[t] = bv; si[t] = bi; __syncthreads();
  for (int st = 128; st > 0; st >>= 1) {
    if (t < st) {
      float v2 = sv[t + st]; int i2 = si[t + st];
      if (v2 > sv[t] || (v2 == sv[t] && i2 < si[t])) { sv[t] = v2; si[t] = i2; }
    }
    __syncthreads();
  }
  if (t == 0) {
    int en = si[0];
    p_end[0] = (float)en;
    p_e0[0] = (float)isc[0];
    p_e1[0] = (float)en;
  }
}

// ===================== launch =====================
extern "C" void kernel_launch(void* const* d_in, const int* in_sizes, int n_in,
                              void* d_out, int out_size, void* d_ws, size_t ws_size,
                              hipStream_t stream) {
  const float* x    = (const float*)d_in[0];
  const float* cand = (const float*)d_in[1];
  const int*   ei   = (const int*)d_in[2];
  const float* W1 = (const float*)d_in[3];  const float* b1  = (const float*)d_in[4];
  const float* W2 = (const float*)d_in[5];  const float* b2  = (const float*)d_in[6];
  const float* W3 = (const float*)d_in[7];  const float* b3  = (const float*)d_in[8];
  const float* Ws1= (const float*)d_in[9];  const float* bs1 = (const float*)d_in[10];
  const float* Ws2= (const float*)d_in[11]; const float* bs2 = (const float*)d_in[12];
  const float* We1= (const float*)d_in[13]; const float* be1 = (const float*)d_in[14];
  const float* We2= (const float*)d_in[15]; const float* be2 = (const float*)d_in[16];

  const int nG = in_sizes[0] / 32, nC = in_sizes[1] / 32;
  const int n  = nG + nC;            // 101000
  const int ne = in_sizes[2] / 2;    // 3200000

  float* out = (float*)d_out;
  const size_t OFF1 = (size_t)n * 32;
  const size_t OFF2 = OFF1 + n;
  const size_t OFF3 = OFF2 + n;
  const size_t OFF4 = OFF3 + 1;
  const size_t OFF5 = OFF4 + 1;     // edge_index_new region: 2*(ne+1) floats

  // ---- workspace layout ----
  float* wf = (float*)d_ws;
  int*   wi = (int*)d_ws;
  size_t NP = (((size_t)n + 2) + 63) & ~(size_t)63;
  size_t o = 0;
  int*   rp    = wi + o; o += NP;
  int*   bsums = wi + o; o += 384;
  float* dinv  = wf + o; o += NP;
  float* bufX  = wf + o; o += (size_t)n * 32 + 64;
  float* bufT  = wf + o; o += (size_t)n * 32 + 64;
  float* slogv = wf + o; o += NP;
  float* elogv = wf + o; o += NP;
  float* pmax  = wf + o; o += 512;
  float* psum  = wf + o; o += 512;
  float* aval  = wf + o; o += 512;
  int*   aidx  = wi + o; o += 512;
  float* fsc   = wf + o; o += 64;
  int*   isc   = wi + o; o += 64;

  // CSR bucket-sort scratch:
  //  - pairs (2*ne ints = 25.6 MB) aliases bufX+bufT (contiguous, 25.87 MB); consumed by
  //    bbuild_k BEFORE gemm L1 writes bufT.
  //  - csr (ne ints) + hist (H+1 ints) live in the edge_index_new out-region
  //    (2*(ne+1) floats = 25.6 MB), overwritten by edgecopy at the end.
  int2* pairs = (int2*)bufX;
  int*  csr   = (int*)(out + OFF5);
  int*  hist  = csr + ne;

  const int* row = ei;
  const int* col = ei + ne;

  const int NBKT = (n + BNODES - 1) / BNODES;            // 395
  const int NBLK = (ne + EPB - 1) / EPB;                 // 782
  const int H    = NBKT * NBLK;                          // ~309K
  const int nbh  = (H + 1023) / 1024;                    // ~302 (<=1024 for scan_single)

  int gN = (n + TPB - 1) / TPB;
  int ne4 = ne / 4;

  // ---- CSR build: bucket sort with LDS atomics only ----
  hist_k<<<NBLK, TPB, 0, stream>>>(col, hist, ne, NBKT, NBLK);
  scan1_k<<<nbh, TPB, 0, stream>>>(hist, bsums, H);
  scan_single_k<<<1, TPB, 0, stream>>>(bsums, nbh);
  scan3_k<<<nbh, TPB, 0, stream>>>(hist, bsums, hist, H, nbh);   // in-place excl scan, hist[H]=ne
  bscatter_k<<<NBLK, TPB, 0, stream>>>(row, col, hist, pairs, ne, NBKT, NBLK);
  bbuild_k<<<NBKT, TPB, 0, stream>>>(pairs, hist, NBLK, rp, dinv, csr, n, ne);

  // ---- GCN stack ----
  gemm_k<32, 16, 16, 0><<<(n + 15) / 16, TPB, 0, stream>>>(x, cand, nG, W1, nullptr, dinv, bufT, n);
  agg4_k<16, 4><<<(n + 3) / 4, TPB, 0, stream>>>((const float4*)bufT, csr, rp, dinv,
                                                 (const float4*)b1, (float4*)bufX, n);
  gemm_k<16, 24, 32, 0><<<(n + 7) / 8, TPB, 0, stream>>>(bufX, bufX, n, W2, nullptr, dinv, bufT, n);
  agg4_k<24, 8><<<(n + 3) / 4, TPB, 0, stream>>>((const float4*)bufT, csr, rp, dinv,
                                                 (const float4*)b2, (float4*)bufX, n);
  gemm_k<24, 32, 32, 0><<<(n + 7) / 8, TPB, 0, stream>>>(bufX, bufX, n, W3, nullptr, dinv, bufT, n);
  agg4_k<32, 8><<<(n + 3) / 4, TPB, 0, stream>>>((const float4*)bufT, csr, rp, dinv,
                                                 (const float4*)b3, (float4*)out, n);

  // edge copy (overwrites csr + hist scratch)
  if (ne % 4 == 0) {
    edgecopy4_k<<<(ne4 + TPB - 1) / TPB, TPB, 0, stream>>>((const int4*)ei, out + OFF5, ne);
  } else {
    edgecopy_sc_k<<<(2 * ne + TPB - 1) / TPB, TPB, 0, stream>>>(ei, out + OFF5, ne);
  }

  // heads
  gemm_k<32, 16, 16, 1><<<(n + 15) / 16, TPB, 0, stream>>>(out, out, n, Ws1, bs1, dinv, bufX, n);
  gemm_k<32, 24, 32, 1><<<(n + 7) / 8, TPB, 0, stream>>>(out, out, n, We1, be1, dinv, bufT, n);
  head2_k<<<gN, TPB, 0, stream>>>(bufX, bufT, Ws2, bs2, We2, be2, slogv, elogv, n);

  // softmax reductions (both heads together)
  rmax_k<<<256, TPB, 0, stream>>>(slogv, elogv, pmax, pmax + 256, n);
  rmax_fin_k<<<1, TPB, 0, stream>>>(pmax, pmax + 256, fsc, 256);
  rsum_k<<<256, TPB, 0, stream>>>(slogv, elogv, fsc, psum, psum + 256, n);
  rsum_fin_k<<<1, TPB, 0, stream>>>(psum, psum + 256, fsc, 256);

  // start head: probs -> categorical(key 42)
  probs_start_k<<<gN, TPB, 0, stream>>>(slogv, fsc, out + OFF1, n, nG);
  argmax_k<<<256, TPB, 0, stream>>>(out + OFF1, 42u, n, aval, aidx);
  argmax_fin_k<<<1, TPB, 0, stream>>>(aval, aidx, 256, isc, out + OFF3);

  // end head: probs (zero at start_node) -> categorical(key 43)
  probs_end_k<<<gN, TPB, 0, stream>>>(elogv, fsc, isc, out + OFF2, n);
  argmax_k<<<256, TPB, 0, stream>>>(out + OFF2, 43u, n, aval + 256, aidx + 256);
  argmax_fin_end_k<<<1, TPB, 0, stream>>>(aval + 256, aidx + 256, 256, isc,
                                          out + OFF4, out + OFF5 + ne, out + OFF5 + 2 * (size_t)ne + 1);
}